// Round 1
// baseline (1101.190 us; speedup 1.0000x reference)
//
#include <hip/hip_runtime.h>

#define NU 4096
#define NI 8192
#define ND 64
#define NTOT 12288

__device__ __forceinline__ unsigned short f2bf(float f) {
    union { float f; unsigned int u; } v; v.f = f;
    unsigned int u = v.u;
    u += 0x7FFFu + ((u >> 16) & 1u);   // round-to-nearest-even
    return (unsigned short)(u >> 16);
}

typedef short frag8 __attribute__((ext_vector_type(8)));
typedef float f32x4 __attribute__((ext_vector_type(4)));

// ---------------------------------------------------------------------------
// K0: read int32 adjacency once. Emit A (bf16, row-major U x I), AT (bf16,
// row-major I x U, via LDS transpose), and integer degree sums.
// ---------------------------------------------------------------------------
__global__ __launch_bounds__(256) void k_prep(const int* __restrict__ edge,
        unsigned short* __restrict__ Abf, unsigned short* __restrict__ ATbf,
        int* __restrict__ deg_u, int* __restrict__ deg_i) {
    __shared__ __align__(16) unsigned short lt[64][72];  // transposed tile [item][user]
    __shared__ int red[256];
    const int t  = threadIdx.x;
    const int u0 = blockIdx.y * 64, i0 = blockIdx.x * 64;
    const int r = t >> 2, q = t & 3;           // row 0..63, col-quarter 0..3

    const int4* ep = (const int4*)(edge + (long)(u0 + r) * NI + i0 + q * 16);
    int rowsum = 0;
    #pragma unroll
    for (int m = 0; m < 4; m++) {
        int4 v = ep[m];
        rowsum += v.x + v.y + v.z + v.w;
        ushort4 b;
        b.x = v.x ? 0x3F80 : 0; b.y = v.y ? 0x3F80 : 0;
        b.z = v.z ? 0x3F80 : 0; b.w = v.w ? 0x3F80 : 0;
        *((ushort4*)(Abf + (long)(u0 + r) * NI + i0 + q * 16 + m * 4)) = b;
        int cb = q * 16 + m * 4;
        lt[cb + 0][r] = b.x; lt[cb + 1][r] = b.y;
        lt[cb + 2][r] = b.z; lt[cb + 3][r] = b.w;
    }
    red[t] = rowsum;
    __syncthreads();
    if (t < 64)
        atomicAdd(&deg_u[u0 + t], red[t*4] + red[t*4+1] + red[t*4+2] + red[t*4+3]);
    __syncthreads();

    // column sums from the transposed tile
    const int c = t >> 2, q2 = t & 3;
    int cs = 0;
    #pragma unroll
    for (int j = 0; j < 16; j++) cs += (lt[c][q2 * 16 + j] != 0);
    red[t] = cs;
    __syncthreads();
    if (t < 64)
        atomicAdd(&deg_i[i0 + t], red[t*4] + red[t*4+1] + red[t*4+2] + red[t*4+3]);

    // write AT tile (coalesced rows of AT)
    #pragma unroll
    for (int m = 0; m < 4; m++) {
        ushort4 w = *((ushort4*)&lt[c][q2 * 16 + m * 4]);
        *((ushort4*)(ATbf + (long)(i0 + c) * NU + u0 + q2 * 16 + m * 4)) = w;
    }
}

// ---------------------------------------------------------------------------
// K1: build layer-0 B operands, stored EMBEDDING-MAJOR (64 x K):
//   BuT[n][u] = bf16(du_scale[u] * x[u][n])        (users rows of input x)
//   BiT[n][i] = bf16(di_scale[i] * x[NU+i][n])     (item rows of input x)
// ---------------------------------------------------------------------------
__global__ __launch_bounds__(256) void k_scale0(const float* __restrict__ x,
        const int* __restrict__ deg_u, const int* __restrict__ deg_i,
        unsigned short* __restrict__ BuT, unsigned short* __restrict__ BiT) {
    __shared__ __align__(16) unsigned short lt[64][72];
    const int t = threadIdx.x;
    const int r0 = blockIdx.x * 64;
    #pragma unroll
    for (int j = 0; j < 4; j++) {
        int id = t + 256 * j;
        int row = id >> 4, c4 = id & 15;
        int gr = r0 + row;
        int dg = (gr < NU) ? deg_u[gr] : deg_i[gr - NU];
        float s = dg > 0 ? rsqrtf((float)dg) : 0.0f;
        float4 v = *((const float4*)(x + (long)gr * ND + c4 * 4));
        lt[c4*4+0][row] = f2bf(v.x * s);
        lt[c4*4+1][row] = f2bf(v.y * s);
        lt[c4*4+2][row] = f2bf(v.z * s);
        lt[c4*4+3][row] = f2bf(v.w * s);
    }
    __syncthreads();
    const int n = t >> 2, q = t & 3;
    unsigned short* dst; long stride; int col0;
    if (r0 < NU) { dst = BuT; stride = NU; col0 = r0; }
    else         { dst = BiT; stride = NI; col0 = r0 - NU; }
    #pragma unroll
    for (int m = 0; m < 4; m++) {
        ushort4 w = *((ushort4*)&lt[n][q * 16 + m * 4]);
        *((ushort4*)(dst + (long)n * stride + col0 + q * 16 + m * 4)) = w;
    }
}

// ---------------------------------------------------------------------------
// K2: one launch per layer. Blocks with r0 <  NI: ytop rows (AT @ Bu),
//     blocks with r0 >= NI: ybot rows (A @ Bi). 64x64 output tile per block.
//     Epilogue: output scale, acc/out handling, next-layer B^T emission.
// ---------------------------------------------------------------------------
__global__ __launch_bounds__(256) void k_gemm(
        const unsigned short* __restrict__ ATbf, const unsigned short* __restrict__ Abf,
        const unsigned short* __restrict__ BuT,  const unsigned short* __restrict__ BiT,
        const int* __restrict__ deg_u, const int* __restrict__ deg_i,
        float* __restrict__ accbuf, unsigned short* __restrict__ BuTn,
        unsigned short* __restrict__ BiTn, float* __restrict__ out, int layer) {
    __shared__ __align__(16) unsigned short At[64][72];
    __shared__ __align__(16) unsigned short Bt[64][72];
    const int t = threadIdx.x;
    const int r0 = blockIdx.x * 64;
    const unsigned short *Ap, *Bp;
    int K;
    if (r0 < NI) { Ap = ATbf + (long)r0 * NU;        Bp = BuT; K = NU; }
    else         { Ap = Abf  + (long)(r0 - NI) * NI; Bp = BiT; K = NI; }

    const int lane = t & 63, w = t >> 6;
    f32x4 acc[4];
    #pragma unroll
    for (int i = 0; i < 4; i++) acc[i] = f32x4{0.f, 0.f, 0.f, 0.f};

    for (int k0 = 0; k0 < K; k0 += 64) {
        __syncthreads();
        #pragma unroll
        for (int j = 0; j < 4; j++) {
            int id = t + 256 * j;
            int row = id >> 4, c4 = id & 15;
            *((ushort4*)&At[row][c4*4]) = *((const ushort4*)(Ap + (long)row * K + k0 + c4*4));
            *((ushort4*)&Bt[row][c4*4]) = *((const ushort4*)(Bp + (long)row * K + k0 + c4*4));
        }
        __syncthreads();
        #pragma unroll
        for (int s = 0; s < 2; s++) {
            frag8 af = *((const frag8*)&At[w*16 + (lane & 15)][s*32 + (lane >> 4)*8]);
            #pragma unroll
            for (int nt = 0; nt < 4; nt++) {
                frag8 bfr = *((const frag8*)&Bt[nt*16 + (lane & 15)][s*32 + (lane >> 4)*8]);
                acc[nt] = __builtin_amdgcn_mfma_f32_16x16x32_bf16(af, bfr, acc[nt], 0, 0, 0);
            }
        }
    }
    __syncthreads();   // protect At before reuse as y-stash

    // per-row scales: so = output scale, fn = next-layer input scale
    float so[4], fn[4];
    #pragma unroll
    for (int jj = 0; jj < 4; jj++) {
        int grow = r0 + w*16 + ((lane >> 4) << 2) + jj;
        if (r0 < NI) { int d = deg_i[grow];      so[jj] = d > 0 ? rsqrtf((float)d) : 0.f; }
        else         { int d = deg_u[grow - NI]; so[jj] = d > 0 ? rsqrtf((float)d) : 0.f; }
        if (r0 < NU) { int d = deg_u[grow];      fn[jj] = d > 0 ? rsqrtf((float)d) : 0.f; }
        else         { int d = deg_i[grow - NU]; fn[jj] = d > 0 ? rsqrtf((float)d) : 0.f; }
    }

    #pragma unroll
    for (int nt = 0; nt < 4; nt++) {
        #pragma unroll
        for (int jj = 0; jj < 4; jj++) {
            int lrow = w*16 + ((lane >> 4) << 2) + jj;
            int grow = r0 + lrow;
            int col  = nt*16 + (lane & 15);
            float y = so[jj] * acc[nt][jj];
            long oidx = (long)grow * ND + col;
            if (layer == 0)      accbuf[oidx] = y;
            else if (layer == 1) accbuf[oidx] += y;
            else                 out[oidx] = (accbuf[oidx] + y) * 0.25f;
            if (layer != 2) At[col][lrow] = f2bf(fn[jj] * y);
        }
    }

    if (layer != 2) {
        __syncthreads();
        unsigned short* dst; long stride; int col0;
        // top rows < NU feed Bu_next[u]=r ; all other rows feed Bi_next[r-NU]
        if (r0 < NU) { dst = BuTn; stride = NU; col0 = r0; }
        else         { dst = BiTn; stride = NI; col0 = r0 - NU; }
        const int n = t >> 2, q = t & 3;
        #pragma unroll
        for (int m = 0; m < 4; m++) {
            ushort4 wv = *((ushort4*)&At[n][q*16 + m*4]);
            *((ushort4*)(dst + (long)n * stride + col0 + q*16 + m*4)) = wv;
        }
    }
}

extern "C" void kernel_launch(void* const* d_in, const int* in_sizes, int n_in,
                              void* d_out, int out_size, void* d_ws, size_t ws_size,
                              hipStream_t stream) {
    (void)in_sizes; (void)n_in; (void)out_size; (void)ws_size;
    const float* x   = (const float*)d_in[0];
    const int*  edge = (const int*)d_in[1];
    float* out = (float*)d_out;

    char* ws = (char*)d_ws;
    size_t off = 0;
    unsigned short* ATbf = (unsigned short*)(ws + off); off += (size_t)NI * NU * 2;   // 64 MiB
    unsigned short* Abf  = (unsigned short*)(ws + off); off += (size_t)NU * NI * 2;   // 64 MiB
    int* deg_u = (int*)(ws + off); off += (size_t)NU * 4;
    int* deg_i = (int*)(ws + off); off += (size_t)NI * 4;
    unsigned short* BuT0 = (unsigned short*)(ws + off); off += (size_t)ND * NU * 2;
    unsigned short* BuT1 = (unsigned short*)(ws + off); off += (size_t)ND * NU * 2;
    unsigned short* BiT0 = (unsigned short*)(ws + off); off += (size_t)ND * NI * 2;
    unsigned short* BiT1 = (unsigned short*)(ws + off); off += (size_t)ND * NI * 2;
    float* acc = (float*)(ws + off); off += (size_t)NTOT * ND * 4;

    hipMemsetAsync(deg_u, 0, (NU + NI) * sizeof(int), stream);
    k_prep<<<dim3(NI / 64, NU / 64), 256, 0, stream>>>(edge, Abf, ATbf, deg_u, deg_i);
    k_scale0<<<NTOT / 64, 256, 0, stream>>>(x, deg_u, deg_i, BuT0, BiT0);
    k_gemm<<<NTOT / 64, 256, 0, stream>>>(ATbf, Abf, BuT0, BiT0, deg_u, deg_i,
                                          acc, BuT1, BiT1, out, 0);
    k_gemm<<<NTOT / 64, 256, 0, stream>>>(ATbf, Abf, BuT1, BiT1, deg_u, deg_i,
                                          acc, BuT0, BiT0, out, 1);
    k_gemm<<<NTOT / 64, 256, 0, stream>>>(ATbf, Abf, BuT0, BiT0, deg_u, deg_i,
                                          acc, (unsigned short*)nullptr,
                                          (unsigned short*)nullptr, out, 2);
}

// Round 2
// 386.372 us; speedup vs baseline: 2.8501x; 2.8501x over previous
//
#include <hip/hip_runtime.h>

#define NU 4096
#define NI 8192
#define ND 64
#define NTOT 12288

typedef unsigned short u16;

__device__ __forceinline__ u16 f2bf(float f) {
    union { float f; unsigned int u; } v; v.f = f;
    unsigned int u = v.u;
    u += 0x7FFFu + ((u >> 16) & 1u);   // round-to-nearest-even
    return (u16)(u >> 16);
}

typedef short frag8 __attribute__((ext_vector_type(8)));
typedef float f32x4 __attribute__((ext_vector_type(4)));

// ---------------------------------------------------------------------------
// K0: read int32 adjacency once. Register 4x4 transpose (no LDS conflicts).
// Emits A (bf16 row-major UxI), AT (bf16 row-major IxU), degree sums.
// ---------------------------------------------------------------------------
__global__ __launch_bounds__(256) void k_prep(const int* __restrict__ edge,
        u16* __restrict__ Abf, u16* __restrict__ ATbf,
        int* __restrict__ deg_u, int* __restrict__ deg_i) {
    __shared__ int csum[64];
    const int t  = threadIdx.x;
    const int u0 = blockIdx.y * 64, i0 = blockIdx.x * 64;
    const int r4 = t >> 4, c4 = t & 15;
    if (t < 64) csum[t] = 0;
    __syncthreads();

    int4 v[4];
    u16 bb[4][4];
    int rs[4];
    #pragma unroll
    for (int j = 0; j < 4; j++) {
        v[j] = *(const int4*)(edge + (long)(u0 + r4*4 + j) * NI + i0 + c4*4);
        bb[j][0] = v[j].x ? 0x3F80 : 0; bb[j][1] = v[j].y ? 0x3F80 : 0;
        bb[j][2] = v[j].z ? 0x3F80 : 0; bb[j][3] = v[j].w ? 0x3F80 : 0;
        rs[j] = v[j].x + v[j].y + v[j].z + v[j].w;
        ushort4 a; a.x = bb[j][0]; a.y = bb[j][1]; a.z = bb[j][2]; a.w = bb[j][3];
        *(ushort4*)(Abf + (long)(u0 + r4*4 + j) * NI + i0 + c4*4) = a;
    }
    // transposed writes: AT row = item, contiguous in u
    #pragma unroll
    for (int k = 0; k < 4; k++) {
        ushort4 w; w.x = bb[0][k]; w.y = bb[1][k]; w.z = bb[2][k]; w.w = bb[3][k];
        *(ushort4*)(ATbf + (long)(i0 + c4*4 + k) * NU + u0 + r4*4) = w;
    }
    // row sums: reduce across the 16 c4 lanes
    #pragma unroll
    for (int m = 1; m < 16; m <<= 1) {
        #pragma unroll
        for (int j = 0; j < 4; j++) rs[j] += __shfl_xor(rs[j], m, 64);
    }
    if ((t & 15) == 0) {
        #pragma unroll
        for (int j = 0; j < 4; j++) atomicAdd(&deg_u[u0 + r4*4 + j], rs[j]);
    }
    // col sums: reduce across r4 groups within wave, then LDS across waves
    int cs[4];
    #pragma unroll
    for (int k = 0; k < 4; k++) {
        const int* vv0 = (const int*)&v[0]; const int* vv1 = (const int*)&v[1];
        const int* vv2 = (const int*)&v[2]; const int* vv3 = (const int*)&v[3];
        cs[k] = vv0[k] + vv1[k] + vv2[k] + vv3[k];
    }
    #pragma unroll
    for (int k = 0; k < 4; k++) {
        cs[k] += __shfl_xor(cs[k], 16, 64);
        cs[k] += __shfl_xor(cs[k], 32, 64);
    }
    if ((t & 63) < 16) {
        #pragma unroll
        for (int k = 0; k < 4; k++) atomicAdd(&csum[c4*4 + k], cs[k]);
    }
    __syncthreads();
    if (t < 64) atomicAdd(&deg_i[i0 + t], csum[t]);
}

// ---------------------------------------------------------------------------
// K1: degree->scale arrays + layer-0 B operands, embedding-major (64 x K).
// ---------------------------------------------------------------------------
__global__ __launch_bounds__(256) void k_scale0(const float* __restrict__ x,
        const int* __restrict__ deg_u, const int* __restrict__ deg_i,
        float* __restrict__ dsu, float* __restrict__ dsi,
        u16* __restrict__ BuT, u16* __restrict__ BiT) {
    const int t = threadIdx.x;
    const int r0 = blockIdx.x * 64;
    const int r4 = t >> 4, c4 = t & 15;
    if (t < 64) {
        int gr = r0 + t;
        int d = (gr < NU) ? deg_u[gr] : deg_i[gr - NU];
        float sc = d > 0 ? rsqrtf((float)d) : 0.f;
        if (gr < NU) dsu[gr] = sc; else dsi[gr - NU] = sc;
    }
    float y[4][4];
    #pragma unroll
    for (int j = 0; j < 4; j++) {
        int gr = r0 + r4*4 + j;
        int d = (gr < NU) ? deg_u[gr] : deg_i[gr - NU];
        float sc = d > 0 ? rsqrtf((float)d) : 0.f;
        float4 xv = *(const float4*)(x + (long)gr * ND + c4*4);
        y[j][0] = xv.x * sc; y[j][1] = xv.y * sc;
        y[j][2] = xv.z * sc; y[j][3] = xv.w * sc;
    }
    u16* dst; long stride; int col0;
    if (r0 < NU) { dst = BuT; stride = NU; col0 = r0; }
    else         { dst = BiT; stride = NI; col0 = r0 - NU; }
    #pragma unroll
    for (int k = 0; k < 4; k++) {
        ushort4 w;
        w.x = f2bf(y[0][k]); w.y = f2bf(y[1][k]);
        w.z = f2bf(y[2][k]); w.w = f2bf(y[3][k]);
        *(ushort4*)(dst + (long)(c4*4 + k) * stride + col0 + r4*4) = w;
    }
}

// ---------------------------------------------------------------------------
// K2: split-K partial GEMM. grid = 256<<s blocks.
//   bx < 128<<s : top (AT @ Bu), tile=bx>>s, chunk=bx&(2^s-1), K chunk 4096>>s
//   else        : bottom (A @ Bi), 2^(s+1) chunks of 8192, same chunk length
// Writes fp32 partials (no scaling).
// ---------------------------------------------------------------------------
__global__ __launch_bounds__(256) void k_gemm_part(
        const u16* __restrict__ ATbf, const u16* __restrict__ Abf,
        const u16* __restrict__ BuT,  const u16* __restrict__ BiT,
        float* __restrict__ Ptop, float* __restrict__ Pbot, int s) {
    __shared__ __align__(16) u16 At[64][72];
    __shared__ __align__(16) u16 Bt[64][72];
    const int t  = threadIdx.x;
    const int bx = blockIdx.x;
    const int nct128 = 128 << s;
    const int ck = 4096 >> s;            // chunk K-length (same both halves)
    const u16 *Ap, *Bp;
    long lda, bstr;
    float* Pout;
    if (bx < nct128) {
        int tile = bx >> s, chunk = bx & ((1 << s) - 1);
        int r0 = tile * 64;
        Ap = ATbf + (long)r0 * NU + chunk * ck; lda = NU;
        Bp = BuT + chunk * ck;                  bstr = NU;
        Pout = Ptop + ((long)chunk * NI + r0) * ND;
    } else {
        int b2 = bx - nct128;
        int tile = b2 >> (s + 1), chunk = b2 & ((2 << s) - 1);
        int r0 = tile * 64;
        Ap = Abf + (long)r0 * NI + chunk * ck;  lda = NI;
        Bp = BiT + chunk * ck;                  bstr = NI;
        Pout = Pbot + ((long)chunk * NU + r0) * ND;
    }

    const int lane = t & 63, w = t >> 6;
    f32x4 acc[4];
    #pragma unroll
    for (int i = 0; i < 4; i++) acc[i] = f32x4{0.f, 0.f, 0.f, 0.f};

    for (int k0 = 0; k0 < ck; k0 += 64) {
        __syncthreads();
        #pragma unroll
        for (int j = 0; j < 4; j++) {
            int id = t + 256 * j;
            int row = id >> 4, cc = (id & 15) * 4;
            *(ushort4*)&At[row][cc] = *(const ushort4*)(Ap + (long)row * lda + k0 + cc);
            *(ushort4*)&Bt[row][cc] = *(const ushort4*)(Bp + (long)row * bstr + k0 + cc);
        }
        __syncthreads();
        #pragma unroll
        for (int sh = 0; sh < 2; sh++) {
            frag8 af = *((const frag8*)&At[w*16 + (lane & 15)][sh*32 + (lane >> 4)*8]);
            #pragma unroll
            for (int nt = 0; nt < 4; nt++) {
                frag8 bfr = *((const frag8*)&Bt[nt*16 + (lane & 15)][sh*32 + (lane >> 4)*8]);
                acc[nt] = __builtin_amdgcn_mfma_f32_16x16x32_bf16(af, bfr, acc[nt], 0, 0, 0);
            }
        }
    }
    #pragma unroll
    for (int nt = 0; nt < 4; nt++) {
        #pragma unroll
        for (int jj = 0; jj < 4; jj++) {
            int lrow = w*16 + ((lane >> 4) << 2) + jj;
            Pout[(long)lrow * ND + nt*16 + (lane & 15)] = acc[nt][jj];
        }
    }
}

// ---------------------------------------------------------------------------
// K3: reduce partials, apply output scale, acc/out logic, emit next-layer
// B operands (register 4x4 transpose).
// ---------------------------------------------------------------------------
__global__ __launch_bounds__(256) void k_reduce(
        const float* __restrict__ Ptop, const float* __restrict__ Pbot,
        const float* __restrict__ dsu, const float* __restrict__ dsi,
        float* __restrict__ accbuf, u16* __restrict__ BuTn,
        u16* __restrict__ BiTn, float* __restrict__ out, int layer, int s) {
    const int t = threadIdx.x;
    const int r0 = blockIdx.x * 64;
    const int r4 = t >> 4, c4 = t & 15;
    float y[4][4];
    #pragma unroll
    for (int j = 0; j < 4; j++) {
        const int grow = r0 + r4*4 + j;
        float sx = 0.f, sy = 0.f, sz = 0.f, sw = 0.f, so;
        if (r0 < NI) {
            const int nc = 1 << s;
            const float* p = Ptop + (long)grow * ND + c4*4;
            for (int c = 0; c < nc; c++) {
                float4 v = *(const float4*)(p + (long)c * NI * ND);
                sx += v.x; sy += v.y; sz += v.z; sw += v.w;
            }
            so = dsi[grow];
        } else {
            const int nc = 2 << s;
            const float* p = Pbot + (long)(grow - NI) * ND + c4*4;
            for (int c = 0; c < nc; c++) {
                float4 v = *(const float4*)(p + (long)c * NU * ND);
                sx += v.x; sy += v.y; sz += v.z; sw += v.w;
            }
            so = dsu[grow - NI];
        }
        y[j][0] = sx * so; y[j][1] = sy * so; y[j][2] = sz * so; y[j][3] = sw * so;
    }
    // acc / out
    #pragma unroll
    for (int j = 0; j < 4; j++) {
        const int grow = r0 + r4*4 + j;
        long o = (long)grow * ND + c4*4;
        float4 w;
        if (layer == 0) {
            w.x = y[j][0]; w.y = y[j][1]; w.z = y[j][2]; w.w = y[j][3];
            *(float4*)(accbuf + o) = w;
        } else if (layer == 1) {
            float4 a = *(const float4*)(accbuf + o);
            w.x = a.x + y[j][0]; w.y = a.y + y[j][1];
            w.z = a.z + y[j][2]; w.w = a.w + y[j][3];
            *(float4*)(accbuf + o) = w;
        } else {
            float4 a = *(const float4*)(accbuf + o);
            w.x = (a.x + y[j][0]) * 0.25f; w.y = (a.y + y[j][1]) * 0.25f;
            w.z = (a.z + y[j][2]) * 0.25f; w.w = (a.w + y[j][3]) * 0.25f;
            *(float4*)(out + o) = w;
        }
    }
    if (layer != 2) {
        float fn[4];
        #pragma unroll
        for (int j = 0; j < 4; j++) {
            int grow = r0 + r4*4 + j;
            fn[j] = (grow < NU) ? dsu[grow] : dsi[grow - NU];
        }
        u16* dst; long stride; int col0;
        if (r0 < NU) { dst = BuTn; stride = NU; col0 = r0; }
        else         { dst = BiTn; stride = NI; col0 = r0 - NU; }
        #pragma unroll
        for (int k = 0; k < 4; k++) {
            ushort4 w;
            w.x = f2bf(y[0][k] * fn[0]); w.y = f2bf(y[1][k] * fn[1]);
            w.z = f2bf(y[2][k] * fn[2]); w.w = f2bf(y[3][k] * fn[3]);
            *(ushort4*)(dst + (long)(c4*4 + k) * stride + col0 + r4*4) = w;
        }
    }
}

extern "C" void kernel_launch(void* const* d_in, const int* in_sizes, int n_in,
                              void* d_out, int out_size, void* d_ws, size_t ws_size,
                              hipStream_t stream) {
    (void)in_sizes; (void)n_in; (void)out_size;
    const float* x    = (const float*)d_in[0];
    const int*   edge = (const int*)d_in[1];
    float* out = (float*)d_out;

    char* ws = (char*)d_ws;
    size_t off = 0;
    u16* ATbf = (u16*)(ws + off); off += (size_t)NI * NU * 2;   // 64 MiB
    u16* Abf  = (u16*)(ws + off); off += (size_t)NU * NI * 2;   // 64 MiB
    int* deg_u = (int*)(ws + off); off += (size_t)NU * 4;
    int* deg_i = (int*)(ws + off); off += (size_t)NI * 4;
    float* dsu = (float*)(ws + off); off += (size_t)NU * 4;
    float* dsi = (float*)(ws + off); off += (size_t)NI * 4;
    u16* BuT0 = (u16*)(ws + off); off += (size_t)ND * NU * 2;
    u16* BuT1 = (u16*)(ws + off); off += (size_t)ND * NU * 2;
    u16* BiT0 = (u16*)(ws + off); off += (size_t)ND * NI * 2;
    u16* BiT1 = (u16*)(ws + off); off += (size_t)ND * NI * 2;
    float* acc = (float*)(ws + off); off += (size_t)NTOT * ND * 4;

    // split-K factor: top 2^s chunks of K=4096, bottom 2^(s+1) of K=8192.
    // partials cost (1<<s)*4 MiB; back off if workspace is tight.
    int s = 3;
    while (s > 0 &&
           off + ((size_t)(1 << s) * (NI + 2 * NU)) * ND * 4 > ws_size) s--;
    float* Ptop = (float*)(ws + off); off += ((size_t)(1 << s) * NI) * ND * 4;
    float* Pbot = (float*)(ws + off); off += ((size_t)(2 << s) * NU) * ND * 4;

    hipMemsetAsync(deg_u, 0, (NU + NI) * sizeof(int), stream);
    k_prep<<<dim3(NI / 64, NU / 64), 256, 0, stream>>>(edge, Abf, ATbf, deg_u, deg_i);
    k_scale0<<<NTOT / 64, 256, 0, stream>>>(x, deg_u, deg_i, dsu, dsi, BuT0, BiT0);

    const int gp = 256 << s;
    k_gemm_part<<<gp, 256, 0, stream>>>(ATbf, Abf, BuT0, BiT0, Ptop, Pbot, s);
    k_reduce<<<NTOT / 64, 256, 0, stream>>>(Ptop, Pbot, dsu, dsi, acc,
                                            BuT1, BiT1, out, 0, s);
    k_gemm_part<<<gp, 256, 0, stream>>>(ATbf, Abf, BuT1, BiT1, Ptop, Pbot, s);
    k_reduce<<<NTOT / 64, 256, 0, stream>>>(Ptop, Pbot, dsu, dsi, acc,
                                            BuT0, BiT0, out, 1, s);
    k_gemm_part<<<gp, 256, 0, stream>>>(ATbf, Abf, BuT0, BiT0, Ptop, Pbot, s);
    k_reduce<<<NTOT / 64, 256, 0, stream>>>(Ptop, Pbot, dsu, dsi, acc,
                                            (u16*)nullptr, (u16*)nullptr, out, 2, s);
}